// Round 2
// baseline (4686.836 us; speedup 1.0000x reference)
//
#include <hip/hip_runtime.h>
#include <hip/hip_bf16.h>
#include <math.h>

// Problem constants (from reference)
#define NB   8
#define LSEQ 1024
#define DM   768
#define DI   1536
#define NST  16
#define DTR  48
#define TT   (NB * LSEQ)   // 8192 tokens per input

__device__ __forceinline__ float silu_f(float x) { return x / (1.f + __expf(-x)); }
__device__ __forceinline__ float softplus_f(float x) { return x > 20.f ? x : log1pf(__expf(x)); }

// ---------------------------------------------------------------------------
// Generic fp32 GEMM: C[M,N] = A[M,K] @ Bw[N,K]^T   (both row-major, K contig)
// EPI: 0 = none, 1 = softplus(x + bias[n])
// 64x64 tile, BK=16, 256 threads, 4x4 per thread.
// ---------------------------------------------------------------------------
template <int EPI>
__global__ __launch_bounds__(256) void gemm_nt(
    const float* __restrict__ A, int lda,
    const float* __restrict__ Bw, int ldb,
    float* __restrict__ C, int ldc,
    int M, int N, int K,
    const float* __restrict__ bias)
{
    __shared__ float As[16][68];
    __shared__ float Bs[16][68];
    const int tid = threadIdx.x;
    const int m0 = blockIdx.y * 64;
    const int n0 = blockIdx.x * 64;
    const int tx = tid & 15;
    const int ty = tid >> 4;
    const int lrow = tid >> 2;          // 0..63
    const int lk4 = (tid & 3) << 2;     // 0,4,8,12

    float acc[4][4] = {};

    for (int k0 = 0; k0 < K; k0 += 16) {
        float4 av = make_float4(0.f, 0.f, 0.f, 0.f);
        float4 bv = make_float4(0.f, 0.f, 0.f, 0.f);
        const int arow = m0 + lrow;
        if (arow < M)
            av = *reinterpret_cast<const float4*>(A + (long)arow * lda + k0 + lk4);
        const int brow = n0 + lrow;
        if (brow < N)
            bv = *reinterpret_cast<const float4*>(Bw + (long)brow * ldb + k0 + lk4);
        __syncthreads();
        As[lk4 + 0][lrow] = av.x; As[lk4 + 1][lrow] = av.y;
        As[lk4 + 2][lrow] = av.z; As[lk4 + 3][lrow] = av.w;
        Bs[lk4 + 0][lrow] = bv.x; Bs[lk4 + 1][lrow] = bv.y;
        Bs[lk4 + 2][lrow] = bv.z; Bs[lk4 + 3][lrow] = bv.w;
        __syncthreads();
        #pragma unroll
        for (int k = 0; k < 16; k++) {
            float a[4], b[4];
            #pragma unroll
            for (int i = 0; i < 4; i++) a[i] = As[k][ty * 4 + i];
            #pragma unroll
            for (int j = 0; j < 4; j++) b[j] = Bs[k][tx * 4 + j];
            #pragma unroll
            for (int i = 0; i < 4; i++)
                #pragma unroll
                for (int j = 0; j < 4; j++)
                    acc[i][j] = fmaf(a[i], b[j], acc[i][j]);
        }
    }

    #pragma unroll
    for (int i = 0; i < 4; i++) {
        const int m = m0 + ty * 4 + i;
        if (m >= M) continue;
        #pragma unroll
        for (int j = 0; j < 4; j++) {
            const int n = n0 + tx * 4 + j;
            if (n >= N) continue;
            float v = acc[i][j];
            if (EPI == 1) v = softplus_f(v + bias[n]);
            C[(long)m * ldc + n] = v;
        }
    }
}

// ---------------------------------------------------------------------------
// Depthwise causal conv (fwd) + anticausal conv (bwd direction of BiMamba),
// both + bias + SiLU. Input xi is the first DI columns of xz (row stride 2*DI).
// fwd:  y[l] = sum_k w[k]  * x[l-3+k]   (zero pad left)
// bwd:  y[l] = sum_k wb[k] * x[l+3-k]   (zero pad right; = reversed causal conv)
// nt = tokens in this chunk (multiple of LSEQ).
// ---------------------------------------------------------------------------
__global__ __launch_bounds__(256) void conv_silu_k(
    const float* __restrict__ xz,
    const float* __restrict__ cw, const float* __restrict__ cb,
    const float* __restrict__ cwb, const float* __restrict__ cbb,
    float* __restrict__ outf, float* __restrict__ outb, int nt)
{
    const long idx = (long)blockIdx.x * 256 + threadIdx.x;
    if (idx >= (long)nt * DI) return;
    const int d = (int)(idx % DI);
    const long t = idx / DI;
    const int l = (int)(t % LSEQ);
    const float* base = xz + t * (2 * DI) + d;

    float af = cb[d];
    float ab = cbb[d];
    #pragma unroll
    for (int k = 0; k < 4; k++) {
        const int dl = k - 3;          // -3..0
        if (l + dl >= 0) af += cw[d * 4 + k] * base[(long)dl * (2 * DI)];
        const int dl2 = 3 - k;         // 3..0
        if (l + dl2 < LSEQ) ab += cwb[d * 4 + k] * base[(long)dl2 * (2 * DI)];
    }
    outf[idx] = silu_f(af);
    outb[idx] = silu_f(ab);
}

// ---------------------------------------------------------------------------
// Selective scan, both directions in one grid (blockIdx.z = dir).
// Lane layout: tid = dg*16 + n  (dg = channel-in-block 0..15, n = state 0..15).
// Each block: one (chunk-local) batch, 16 channels. y is written IN PLACE over
// the dt buffer (each location read exactly once, then overwritten).
// ---------------------------------------------------------------------------
__global__ __launch_bounds__(256) void scan_k(
    const float* __restrict__ uf, float* __restrict__ yf, const float* __restrict__ dblf,
    const float* __restrict__ Alf, const float* __restrict__ Df,
    const float* __restrict__ ub, float* __restrict__ yb, const float* __restrict__ dblb,
    const float* __restrict__ Alb, const float* __restrict__ Db)
{
    const int dir = blockIdx.z;
    const float* u_   = dir ? ub   : uf;
    float*       y_   = dir ? yb   : yf;
    const float* dbl_ = dir ? dblb : dblf;
    const float* Al   = dir ? Alb  : Alf;
    const float* Dp   = dir ? Db   : Df;

    const int tid = threadIdx.x;
    const int n = tid & 15;
    const int dg = tid >> 4;
    const int d = blockIdx.x * 16 + dg;
    const int b = blockIdx.y;

    const float An = -__expf(Al[d * NST + n]);
    const float Dd = Dp[d];
    float h = 0.f;
    const long tbase = (long)b * LSEQ;

    // prefetch step 0
    int l = dir ? (LSEQ - 1) : 0;
    long t = tbase + l;
    float u  = u_[t * DI + d];
    float dt = y_[t * DI + d];
    float Bn = dbl_[t * 80 + DTR + n];
    float Cn = dbl_[t * 80 + DTR + NST + n];

    for (int s = 0; s < LSEQ; s++) {
        // prefetch step s+1 (issued before this step's store)
        const int s2 = s + 1;
        const int l2 = dir ? (LSEQ - 1 - s2) : s2;
        float u2 = 0.f, dt2 = 0.f, B2 = 0.f, C2 = 0.f;
        if (s2 < LSEQ) {
            const long t2 = tbase + l2;
            u2  = u_[t2 * DI + d];
            dt2 = y_[t2 * DI + d];
            B2  = dbl_[t2 * 80 + DTR + n];
            C2  = dbl_[t2 * 80 + DTR + NST + n];
        }
        const float dA = __expf(dt * An);
        h = h * dA + (dt * u) * Bn;
        float p = h * Cn;
        p += __shfl_xor(p, 1, 16);
        p += __shfl_xor(p, 2, 16);
        p += __shfl_xor(p, 4, 16);
        p += __shfl_xor(p, 8, 16);
        if (n == 0) y_[t * DI + d] = p + u * Dd;
        u = u2; dt = dt2; Bn = B2; Cn = C2;
        t = tbase + l2;
    }
}

// ---------------------------------------------------------------------------
// Gate: g = (yf + yb) * silu(z);  z = xz[:, DI + d]
// ---------------------------------------------------------------------------
__global__ __launch_bounds__(256) void gate_k(
    const float* __restrict__ yf, const float* __restrict__ yb,
    const float* __restrict__ xz, float* __restrict__ g, int nt)
{
    const long idx = (long)blockIdx.x * 256 + threadIdx.x;
    if (idx >= (long)nt * DI) return;
    const int d = (int)(idx % DI);
    const long t = idx / DI;
    const float z = xz[t * (2 * DI) + DI + d];
    g[idx] = (yf[idx] + yb[idx]) * silu_f(z);
}

// ---------------------------------------------------------------------------
// out = xin + rmsnorm(mo, w);  one block per token, 256 threads, 3 elems each
// ---------------------------------------------------------------------------
__global__ __launch_bounds__(256) void rmsnorm_res_k(
    const float* __restrict__ mo, const float* __restrict__ xin,
    const float* __restrict__ w, float* __restrict__ out)
{
    const int t = blockIdx.x;
    const int tid = threadIdx.x;
    const long base = (long)t * DM;
    const float v0 = mo[base + tid];
    const float v1 = mo[base + tid + 256];
    const float v2 = mo[base + tid + 512];
    float ss = v0 * v0 + v1 * v1 + v2 * v2;
    #pragma unroll
    for (int m = 1; m < 64; m <<= 1) ss += __shfl_xor(ss, m, 64);
    __shared__ float red[4];
    if ((tid & 63) == 0) red[tid >> 6] = ss;
    __syncthreads();
    const float tot = red[0] + red[1] + red[2] + red[3];
    const float sc = rsqrtf(tot * (1.f / DM) + 1e-5f);
    out[base + tid]       = xin[base + tid]       + v0 * sc * w[tid];
    out[base + tid + 256] = xin[base + tid + 256] + v1 * sc * w[tid + 256];
    out[base + tid + 512] = xin[base + tid + 512] + v2 * sc * w[tid + 512];
}

// ---------------------------------------------------------------------------
extern "C" void kernel_launch(void* const* d_in, const int* in_sizes, int n_in,
                              void* d_out, int out_size, void* d_ws, size_t ws_size,
                              hipStream_t stream)
{
    const float* m_x         = (const float*)d_in[0];
    const float* n_x         = (const float*)d_in[1];
    const float* in_proj_w   = (const float*)d_in[2];
    const float* conv_w      = (const float*)d_in[3];
    const float* conv_b      = (const float*)d_in[4];
    const float* x_proj_w    = (const float*)d_in[5];
    const float* dt_proj_w   = (const float*)d_in[6];
    const float* dt_proj_b   = (const float*)d_in[7];
    const float* A_log       = (const float*)d_in[8];
    const float* Dp          = (const float*)d_in[9];
    const float* conv_w_b    = (const float*)d_in[10];
    const float* conv_b_b    = (const float*)d_in[11];
    const float* x_proj_w_b  = (const float*)d_in[12];
    const float* dt_proj_w_b = (const float*)d_in[13];
    const float* dt_proj_b_b = (const float*)d_in[14];
    const float* A_log_b     = (const float*)d_in[15];
    const float* D_b         = (const float*)d_in[16];
    const float* out_proj_w  = (const float*)d_in[17];
    const float* norm1_w     = (const float*)d_in[18];
    const float* norm2_w     = (const float*)d_in[19];

    // ---- batch-chunked workspace sizing (fits whatever ws_size we're given)
    // per-batch floats: xz 1024*3072, convf/convb 1024*1536 each,
    //                   dblf/dblb 1024*80 each, dtf/dtb 1024*1536 each
    const long PB = (long)LSEQ * (2 * DI + 4 * DI + 2 * 80);  // 9,601,024 floats
    int CB = (int)(ws_size / ((size_t)PB * 4));
    if (CB < 1) CB = 1;
    if (CB > NB) CB = NB;

    const long CT = (long)CB * LSEQ;    // max tokens per chunk
    float* ws    = (float*)d_ws;
    float* xz    = ws;                       // CT * 3072
    float* convf = xz    + CT * 2 * DI;      // CT * 1536
    float* convb = convf + CT * DI;          // CT * 1536
    float* dblf  = convb + CT * DI;          // CT * 80
    float* dblb  = dblf  + CT * 80;          // CT * 80
    float* dtf   = dblb  + CT * 80;          // CT * 1536 (scan overwrites with yf)
    float* dtb   = dtf   + CT * DI;          // CT * 1536 (scan overwrites with yb)
    // reuse after scans: g -> convf, mamba_out -> convb

    const dim3 blk(256);

    for (int which = 0; which < 2; which++) {
        const float* xin0 = which ? n_x : m_x;
        const float* nw   = which ? norm2_w : norm1_w;
        float* out0 = (float*)d_out + (long)which * TT * DM;

        for (int b0 = 0; b0 < NB; b0 += CB) {
            const int cb = (NB - b0) < CB ? (NB - b0) : CB;   // batches this chunk
            const int nt = cb * LSEQ;                          // tokens this chunk
            const float* xin = xin0 + (long)b0 * LSEQ * DM;
            float* outp = out0 + (long)b0 * LSEQ * DM;

            // in_proj: xz[nt,3072] = xin[nt,768] @ in_proj_w[3072,768]^T
            gemm_nt<0><<<dim3((2 * DI) / 64, nt / 64), blk, 0, stream>>>(
                xin, DM, in_proj_w, DM, xz, 2 * DI, nt, 2 * DI, DM, nullptr);

            // depthwise conv + silu, both directions
            conv_silu_k<<<dim3(((long)nt * DI + 255) / 256), blk, 0, stream>>>(
                xz, conv_w, conv_b, conv_w_b, conv_b_b, convf, convb, nt);

            // x_proj: dbl[nt,80] = conv @ x_proj_w[80,1536]^T
            gemm_nt<0><<<dim3(2, nt / 64), blk, 0, stream>>>(
                convf, DI, x_proj_w, DI, dblf, 80, nt, 80, DI, nullptr);
            gemm_nt<0><<<dim3(2, nt / 64), blk, 0, stream>>>(
                convb, DI, x_proj_w_b, DI, dblb, 80, nt, 80, DI, nullptr);

            // dt_proj: dt[nt,1536] = softplus(dbl[:, :48] @ dt_proj_w^T + b)
            gemm_nt<1><<<dim3(DI / 64, nt / 64), blk, 0, stream>>>(
                dblf, 80, dt_proj_w, DTR, dtf, DI, nt, DI, DTR, dt_proj_b);
            gemm_nt<1><<<dim3(DI / 64, nt / 64), blk, 0, stream>>>(
                dblb, 80, dt_proj_w_b, DTR, dtb, DI, nt, DI, DTR, dt_proj_b_b);

            // selective scan, fwd + bwd (y overwrites dt buffers)
            scan_k<<<dim3(DI / 16, cb, 2), blk, 0, stream>>>(
                convf, dtf, dblf, A_log, Dp,
                convb, dtb, dblb, A_log_b, D_b);

            // gate: g = (yf + yb) * silu(z)   -> reuse convf
            gate_k<<<dim3(((long)nt * DI + 255) / 256), blk, 0, stream>>>(
                dtf, dtb, xz, convf, nt);

            // out_proj: mo[nt,768] = g @ out_proj_w[768,1536]^T  -> reuse convb
            gemm_nt<0><<<dim3(DM / 64, nt / 64), blk, 0, stream>>>(
                convf, DI, out_proj_w, DI, convb, DM, nt, DM, DI, nullptr);

            // residual + rmsnorm
            rmsnorm_res_k<<<dim3(nt), blk, 0, stream>>>(convb, xin, nw, outp);
        }
    }
}

// Round 3
// 4184.829 us; speedup vs baseline: 1.1200x; 1.1200x over previous
//
#include <hip/hip_runtime.h>
#include <hip/hip_bf16.h>
#include <math.h>

// Problem constants (from reference)
#define NB   8
#define LSEQ 1024
#define DM   768
#define DI   1536
#define NST  16
#define DTR  48
#define TT   (NB * LSEQ)   // 8192 tokens per input

__device__ __forceinline__ float silu_f(float x) { return x / (1.f + __expf(-x)); }
__device__ __forceinline__ float softplus_f(float x) { return x > 20.f ? x : log1pf(__expf(x)); }

// ---------------------------------------------------------------------------
// Generic fp32 GEMM: C[M,N] = A[M,K] @ Bw[N,K]^T   (both row-major, K contig)
// EPI: 0 = none, 1 = softplus(x + bias[n])
// 64x64 tile, BK=16, 256 threads, 4x4 per thread.
// ---------------------------------------------------------------------------
template <int EPI>
__global__ __launch_bounds__(256) void gemm_nt(
    const float* __restrict__ A, int lda,
    const float* __restrict__ Bw, int ldb,
    float* __restrict__ C, int ldc,
    int M, int N, int K,
    const float* __restrict__ bias)
{
    __shared__ float As[16][68];
    __shared__ float Bs[16][68];
    const int tid = threadIdx.x;
    const int m0 = blockIdx.y * 64;
    const int n0 = blockIdx.x * 64;
    const int tx = tid & 15;
    const int ty = tid >> 4;
    const int lrow = tid >> 2;          // 0..63
    const int lk4 = (tid & 3) << 2;     // 0,4,8,12

    float acc[4][4] = {};

    for (int k0 = 0; k0 < K; k0 += 16) {
        float4 av = make_float4(0.f, 0.f, 0.f, 0.f);
        float4 bv = make_float4(0.f, 0.f, 0.f, 0.f);
        const int arow = m0 + lrow;
        if (arow < M)
            av = *reinterpret_cast<const float4*>(A + (long)arow * lda + k0 + lk4);
        const int brow = n0 + lrow;
        if (brow < N)
            bv = *reinterpret_cast<const float4*>(Bw + (long)brow * ldb + k0 + lk4);
        __syncthreads();
        As[lk4 + 0][lrow] = av.x; As[lk4 + 1][lrow] = av.y;
        As[lk4 + 2][lrow] = av.z; As[lk4 + 3][lrow] = av.w;
        Bs[lk4 + 0][lrow] = bv.x; Bs[lk4 + 1][lrow] = bv.y;
        Bs[lk4 + 2][lrow] = bv.z; Bs[lk4 + 3][lrow] = bv.w;
        __syncthreads();
        #pragma unroll
        for (int k = 0; k < 16; k++) {
            float a[4], b[4];
            #pragma unroll
            for (int i = 0; i < 4; i++) a[i] = As[k][ty * 4 + i];
            #pragma unroll
            for (int j = 0; j < 4; j++) b[j] = Bs[k][tx * 4 + j];
            #pragma unroll
            for (int i = 0; i < 4; i++)
                #pragma unroll
                for (int j = 0; j < 4; j++)
                    acc[i][j] = fmaf(a[i], b[j], acc[i][j]);
        }
    }

    #pragma unroll
    for (int i = 0; i < 4; i++) {
        const int m = m0 + ty * 4 + i;
        if (m >= M) continue;
        #pragma unroll
        for (int j = 0; j < 4; j++) {
            const int n = n0 + tx * 4 + j;
            if (n >= N) continue;
            float v = acc[i][j];
            if (EPI == 1) v = softplus_f(v + bias[n]);
            C[(long)m * ldc + n] = v;
        }
    }
}

// ---------------------------------------------------------------------------
// Depthwise causal conv (fwd) + anticausal conv (bwd direction of BiMamba),
// both + bias + SiLU. Input xi is the first DI columns of xz (row stride 2*DI).
// ---------------------------------------------------------------------------
__global__ __launch_bounds__(256) void conv_silu_k(
    const float* __restrict__ xz,
    const float* __restrict__ cw, const float* __restrict__ cb,
    const float* __restrict__ cwb, const float* __restrict__ cbb,
    float* __restrict__ outf, float* __restrict__ outb, int nt)
{
    const long idx = (long)blockIdx.x * 256 + threadIdx.x;
    if (idx >= (long)nt * DI) return;
    const int d = (int)(idx % DI);
    const long t = idx / DI;
    const int l = (int)(t % LSEQ);
    const float* base = xz + t * (2 * DI) + d;

    float af = cb[d];
    float ab = cbb[d];
    #pragma unroll
    for (int k = 0; k < 4; k++) {
        const int dl = k - 3;          // -3..0
        if (l + dl >= 0) af += cw[d * 4 + k] * base[(long)dl * (2 * DI)];
        const int dl2 = 3 - k;         // 3..0
        if (l + dl2 < LSEQ) ab += cwb[d * 4 + k] * base[(long)dl2 * (2 * DI)];
    }
    outf[idx] = silu_f(af);
    outb[idx] = silu_f(ab);
}

// ---------------------------------------------------------------------------
// Selective scan, both directions in one grid (blockIdx.z = dir).
// Lane layout: tid = dg*16 + n  (dg = channel-in-block 0..15, n = state 0..15).
// 8-step register tiles, double-buffered (A/B named arrays, compile-time
// indices only), so each wave keeps ~8 steps of loads in flight.
// y is written IN PLACE over the dt buffer (tile t's stores never alias
// tile t+1/t+2's loads: different token indices).
// ---------------------------------------------------------------------------
#define TS 8
#define NTILE (LSEQ / TS)

__global__ __launch_bounds__(256) void scan_k(
    const float* __restrict__ uf, float* __restrict__ yf, const float* __restrict__ dblf,
    const float* __restrict__ Alf, const float* __restrict__ Df,
    const float* __restrict__ ub, float* __restrict__ yb, const float* __restrict__ dblb,
    const float* __restrict__ Alb, const float* __restrict__ Db)
{
    const int dir = blockIdx.z;
    const float* u_   = dir ? ub   : uf;
    float*       y_   = dir ? yb   : yf;
    const float* dbl_ = dir ? dblb : dblf;
    const float* Al   = dir ? Alb  : Alf;
    const float* Dp   = dir ? Db   : Df;

    const int tid = threadIdx.x;
    const int n = tid & 15;
    const int dg = tid >> 4;
    const int d = blockIdx.x * 16 + dg;
    const int b = blockIdx.y;

    const float An = -__expf(Al[d * NST + n]);
    const float Dd = Dp[d];
    float h = 0.f;
    const long tbase = (long)b * LSEQ;
    const int stp = dir ? -1 : 1;
    const int l0  = dir ? (LSEQ - 1) : 0;

#define LOADT(U, DT, BV, CV, tile)                                      \
    {                                                                   \
        _Pragma("unroll")                                               \
        for (int i = 0; i < TS; i++) {                                  \
            const int l = l0 + ((tile) * TS + i) * stp;                 \
            const long t = tbase + l;                                   \
            U[i]  = u_[t * DI + d];                                     \
            DT[i] = y_[t * DI + d];                                     \
            BV[i] = dbl_[t * 80 + DTR + n];                             \
            CV[i] = dbl_[t * 80 + DTR + NST + n];                       \
        }                                                               \
    }

#define COMPT(U, DT, BV, CV, tile)                                      \
    {                                                                   \
        _Pragma("unroll")                                               \
        for (int i = 0; i < TS; i++) {                                  \
            const float dAv = __expf(DT[i] * An);                       \
            h = h * dAv + (DT[i] * U[i]) * BV[i];                       \
            float p = h * CV[i];                                        \
            p += __shfl_xor(p, 1, 16);                                  \
            p += __shfl_xor(p, 2, 16);                                  \
            p += __shfl_xor(p, 4, 16);                                  \
            p += __shfl_xor(p, 8, 16);                                  \
            if (n == 0) {                                               \
                const int l = l0 + ((tile) * TS + i) * stp;             \
                y_[(tbase + l) * DI + d] = p + U[i] * Dd;               \
            }                                                           \
        }                                                               \
    }

    float uA[TS], dA_[TS], BA[TS], CA[TS];
    float uB[TS], dB_[TS], BB[TS], CB2[TS];

    LOADT(uA, dA_, BA, CA, 0);
    for (int tile = 0; tile < NTILE; tile += 2) {
        LOADT(uB, dB_, BB, CB2, tile + 1);          // NTILE even: always valid
        COMPT(uA, dA_, BA, CA, tile);
        if (tile + 2 < NTILE) LOADT(uA, dA_, BA, CA, tile + 2);
        COMPT(uB, dB_, BB, CB2, tile + 1);
    }
#undef LOADT
#undef COMPT
}

// ---------------------------------------------------------------------------
// Gate: g = (yf + yb) * silu(z);  z = xz[:, DI + d]
// ---------------------------------------------------------------------------
__global__ __launch_bounds__(256) void gate_k(
    const float* __restrict__ yf, const float* __restrict__ yb,
    const float* __restrict__ xz, float* __restrict__ g, int nt)
{
    const long idx = (long)blockIdx.x * 256 + threadIdx.x;
    if (idx >= (long)nt * DI) return;
    const int d = (int)(idx % DI);
    const long t = idx / DI;
    const float z = xz[t * (2 * DI) + DI + d];
    g[idx] = (yf[idx] + yb[idx]) * silu_f(z);
}

// ---------------------------------------------------------------------------
// out = xin + rmsnorm(mo, w);  one block per token, 256 threads, 3 elems each
// ---------------------------------------------------------------------------
__global__ __launch_bounds__(256) void rmsnorm_res_k(
    const float* __restrict__ mo, const float* __restrict__ xin,
    const float* __restrict__ w, float* __restrict__ out)
{
    const int t = blockIdx.x;
    const int tid = threadIdx.x;
    const long base = (long)t * DM;
    const float v0 = mo[base + tid];
    const float v1 = mo[base + tid + 256];
    const float v2 = mo[base + tid + 512];
    float ss = v0 * v0 + v1 * v1 + v2 * v2;
    #pragma unroll
    for (int m = 1; m < 64; m <<= 1) ss += __shfl_xor(ss, m, 64);
    __shared__ float red[4];
    if ((tid & 63) == 0) red[tid >> 6] = ss;
    __syncthreads();
    const float tot = red[0] + red[1] + red[2] + red[3];
    const float sc = rsqrtf(tot * (1.f / DM) + 1e-5f);
    out[base + tid]       = xin[base + tid]       + v0 * sc * w[tid];
    out[base + tid + 256] = xin[base + tid + 256] + v1 * sc * w[tid + 256];
    out[base + tid + 512] = xin[base + tid + 512] + v2 * sc * w[tid + 512];
}

// ---------------------------------------------------------------------------
extern "C" void kernel_launch(void* const* d_in, const int* in_sizes, int n_in,
                              void* d_out, int out_size, void* d_ws, size_t ws_size,
                              hipStream_t stream)
{
    const float* m_x         = (const float*)d_in[0];
    const float* n_x         = (const float*)d_in[1];
    const float* in_proj_w   = (const float*)d_in[2];
    const float* conv_w      = (const float*)d_in[3];
    const float* conv_b      = (const float*)d_in[4];
    const float* x_proj_w    = (const float*)d_in[5];
    const float* dt_proj_w   = (const float*)d_in[6];
    const float* dt_proj_b   = (const float*)d_in[7];
    const float* A_log       = (const float*)d_in[8];
    const float* Dp          = (const float*)d_in[9];
    const float* conv_w_b    = (const float*)d_in[10];
    const float* conv_b_b    = (const float*)d_in[11];
    const float* x_proj_w_b  = (const float*)d_in[12];
    const float* dt_proj_w_b = (const float*)d_in[13];
    const float* dt_proj_b_b = (const float*)d_in[14];
    const float* A_log_b     = (const float*)d_in[15];
    const float* D_b         = (const float*)d_in[16];
    const float* out_proj_w  = (const float*)d_in[17];
    const float* norm1_w     = (const float*)d_in[18];
    const float* norm2_w     = (const float*)d_in[19];

    // ---- batch-chunked workspace sizing (fits whatever ws_size we're given)
    const long PB = (long)LSEQ * (2 * DI + 4 * DI + 2 * 80);  // floats per batch
    int CB = (int)(ws_size / ((size_t)PB * 4));
    if (CB < 1) CB = 1;
    if (CB > NB) CB = NB;

    const long CT = (long)CB * LSEQ;    // max tokens per chunk
    float* ws    = (float*)d_ws;
    float* xz    = ws;                       // CT * 3072
    float* convf = xz    + CT * 2 * DI;      // CT * 1536
    float* convb = convf + CT * DI;          // CT * 1536
    float* dblf  = convb + CT * DI;          // CT * 80
    float* dblb  = dblf  + CT * 80;          // CT * 80
    float* dtf   = dblb  + CT * 80;          // CT * 1536 (scan overwrites with yf)
    float* dtb   = dtf   + CT * DI;          // CT * 1536 (scan overwrites with yb)
    // reuse after scans: g -> convf, mamba_out -> convb

    const dim3 blk(256);

    for (int which = 0; which < 2; which++) {
        const float* xin0 = which ? n_x : m_x;
        const float* nw   = which ? norm2_w : norm1_w;
        float* out0 = (float*)d_out + (long)which * TT * DM;

        for (int b0 = 0; b0 < NB; b0 += CB) {
            const int cb = (NB - b0) < CB ? (NB - b0) : CB;   // batches this chunk
            const int nt = cb * LSEQ;                          // tokens this chunk
            const float* xin = xin0 + (long)b0 * LSEQ * DM;
            float* outp = out0 + (long)b0 * LSEQ * DM;

            // in_proj: xz[nt,3072] = xin[nt,768] @ in_proj_w[3072,768]^T
            gemm_nt<0><<<dim3((2 * DI) / 64, nt / 64), blk, 0, stream>>>(
                xin, DM, in_proj_w, DM, xz, 2 * DI, nt, 2 * DI, DM, nullptr);

            // depthwise conv + silu, both directions
            conv_silu_k<<<dim3(((long)nt * DI + 255) / 256), blk, 0, stream>>>(
                xz, conv_w, conv_b, conv_w_b, conv_b_b, convf, convb, nt);

            // x_proj: dbl[nt,80] = conv @ x_proj_w[80,1536]^T
            gemm_nt<0><<<dim3(2, nt / 64), blk, 0, stream>>>(
                convf, DI, x_proj_w, DI, dblf, 80, nt, 80, DI, nullptr);
            gemm_nt<0><<<dim3(2, nt / 64), blk, 0, stream>>>(
                convb, DI, x_proj_w_b, DI, dblb, 80, nt, 80, DI, nullptr);

            // dt_proj: dt[nt,1536] = softplus(dbl[:, :48] @ dt_proj_w^T + b)
            gemm_nt<1><<<dim3(DI / 64, nt / 64), blk, 0, stream>>>(
                dblf, 80, dt_proj_w, DTR, dtf, DI, nt, DI, DTR, dt_proj_b);
            gemm_nt<1><<<dim3(DI / 64, nt / 64), blk, 0, stream>>>(
                dblb, 80, dt_proj_w_b, DTR, dtb, DI, nt, DI, DTR, dt_proj_b_b);

            // selective scan, fwd + bwd (y overwrites dt buffers)
            scan_k<<<dim3(DI / 16, cb, 2), blk, 0, stream>>>(
                convf, dtf, dblf, A_log, Dp,
                convb, dtb, dblb, A_log_b, D_b);

            // gate: g = (yf + yb) * silu(z)   -> reuse convf
            gate_k<<<dim3(((long)nt * DI + 255) / 256), blk, 0, stream>>>(
                dtf, dtb, xz, convf, nt);

            // out_proj: mo[nt,768] = g @ out_proj_w[768,1536]^T  -> reuse convb
            gemm_nt<0><<<dim3(DM / 64, nt / 64), blk, 0, stream>>>(
                convf, DI, out_proj_w, DI, convb, DM, nt, DM, DI, nullptr);

            // residual + rmsnorm
            rmsnorm_res_k<<<dim3(nt), blk, 0, stream>>>(convb, xin, nw, outp);
        }
    }
}

// Round 4
// 2682.211 us; speedup vs baseline: 1.7474x; 1.5602x over previous
//
#include <hip/hip_runtime.h>
#include <hip/hip_bf16.h>
#include <math.h>

// Problem constants (from reference)
#define NB   8
#define LSEQ 1024
#define DM   768
#define DI   1536
#define NST  16
#define DTR  48
#define TT   (NB * LSEQ)   // 8192 tokens per input

typedef __attribute__((ext_vector_type(8))) short bf16x8;
typedef __attribute__((ext_vector_type(4))) float f32x4;

__device__ __forceinline__ float silu_f(float x) { return x / (1.f + __expf(-x)); }
__device__ __forceinline__ float softplus_f(float x) { return x > 20.f ? x : log1pf(__expf(x)); }

// ---------------------------------------------------------------------------
// fp32 -> bf16 conversion (n must be a multiple of 4)
// ---------------------------------------------------------------------------
__global__ __launch_bounds__(256) void f2bf_k(
    const float* __restrict__ in, __hip_bfloat16* __restrict__ out, long n4)
{
    const long i = (long)blockIdx.x * 256 + threadIdx.x;
    if (i >= n4) return;
    const float4 v = ((const float4*)in)[i];
    out[i * 4 + 0] = __float2bfloat16(v.x);
    out[i * 4 + 1] = __float2bfloat16(v.y);
    out[i * 4 + 2] = __float2bfloat16(v.z);
    out[i * 4 + 3] = __float2bfloat16(v.w);
}

// ---------------------------------------------------------------------------
// bf16 MFMA GEMM: C[M,N] (fp32) = A[M,K] @ Bw[N,K]^T, A/Bw bf16 row-major,
// K contiguous. 128x128 tile, BK=32, 256 threads = 4 waves (2x2), 4x4
// 16x16x32 fragments per wave. Reg-staged double-buffered LDS with XOR
// swizzle slot^=(row>>1)&3 applied on BOTH write and read sides.
// Requires: M%128==0, N%128==0, K%32==0.
// ---------------------------------------------------------------------------
__global__ __launch_bounds__(256) void gemm_bf16(
    const __hip_bfloat16* __restrict__ A, int lda,
    const __hip_bfloat16* __restrict__ Bw, int ldb,
    float* __restrict__ C, int ldc, int K)
{
    __shared__ short lds[2][8192];      // [buf][ A 128x32 | B 128x32 ] bf16
    const int tid = threadIdx.x;
    const int lane = tid & 63;
    const int wv = tid >> 6;
    const int wm = wv >> 1;             // 0..1
    const int wn = wv & 1;              // 0..1
    const long m0 = (long)blockIdx.y * 128;
    const long n0 = (long)blockIdx.x * 128;

    // --- staging map: thread t covers rows srow, srow+64 of both A and B,
    //     16B chunk skslot of the 64B row. Swizzle is row-periodic mod 8,
    //     identical for srow and srow+64.
    const int srow = tid >> 2;          // 0..63
    const int skslot = tid & 3;
    const int sswz = skslot ^ ((srow >> 1) & 3);
    const __hip_bfloat16* gA0 = A  + (m0 + srow) * (long)lda + skslot * 8;
    const __hip_bfloat16* gA1 = gA0 + 64l * lda;
    const __hip_bfloat16* gB0 = Bw + (n0 + srow) * (long)ldb + skslot * 8;
    const __hip_bfloat16* gB1 = gB0 + 64l * ldb;
    const int wA0 = srow * 32 + sswz * 8;
    const int wA1 = (srow + 64) * 32 + sswz * 8;
    const int wB0 = 4096 + srow * 32 + sswz * 8;
    const int wB1 = 4096 + (srow + 64) * 32 + sswz * 8;

    const int frow = lane & 15;         // fragment row-in-16
    const int fk = lane >> 4;           // fragment k-slot 0..3

    f32x4 acc[4][4] = {};

    const int NK = K / 32;
    int4 r0, r1, r2, r3;
    // prologue: tile 0 -> regs -> LDS buf 0
    r0 = *(const int4*)gA0; r1 = *(const int4*)gA1;
    r2 = *(const int4*)gB0; r3 = *(const int4*)gB1;
    *(int4*)&lds[0][wA0] = r0; *(int4*)&lds[0][wA1] = r1;
    *(int4*)&lds[0][wB0] = r2; *(int4*)&lds[0][wB1] = r3;

    for (int ks = 0; ks < NK; ks++) {
        const int cur = ks & 1;
        if (ks + 1 < NK) {              // issue next tile's global loads early
            const long ko = (long)(ks + 1) * 32;
            r0 = *(const int4*)(gA0 + ko); r1 = *(const int4*)(gA1 + ko);
            r2 = *(const int4*)(gB0 + ko); r3 = *(const int4*)(gB1 + ko);
        }
        __syncthreads();                // staging of `cur` visible to all
        bf16x8 af[4], bfr[4];
        #pragma unroll
        for (int mf = 0; mf < 4; mf++) {
            const int row = wm * 64 + mf * 16 + frow;
            const int sl = fk ^ ((row >> 1) & 3);
            af[mf] = *(const bf16x8*)&lds[cur][row * 32 + sl * 8];
        }
        #pragma unroll
        for (int nf = 0; nf < 4; nf++) {
            const int row = wn * 64 + nf * 16 + frow;
            const int sl = fk ^ ((row >> 1) & 3);
            bfr[nf] = *(const bf16x8*)&lds[cur][4096 + row * 32 + sl * 8];
        }
        #pragma unroll
        for (int mf = 0; mf < 4; mf++)
            #pragma unroll
            for (int nf = 0; nf < 4; nf++)
                acc[mf][nf] = __builtin_amdgcn_mfma_f32_16x16x32_bf16(
                    af[mf], bfr[nf], acc[mf][nf], 0, 0, 0);
        if (ks + 1 < NK) {              // write next tile into other buffer
            const int nb = cur ^ 1;
            *(int4*)&lds[nb][wA0] = r0; *(int4*)&lds[nb][wA1] = r1;
            *(int4*)&lds[nb][wB0] = r2; *(int4*)&lds[nb][wB1] = r3;
        }
    }

    // epilogue: C/D layout col=lane&15, row=(lane>>4)*4+j  [m89-verified]
    #pragma unroll
    for (int mf = 0; mf < 4; mf++) {
        #pragma unroll
        for (int nf = 0; nf < 4; nf++) {
            const long col = n0 + wn * 64 + nf * 16 + (lane & 15);
            const long rw = m0 + wm * 64 + mf * 16 + (lane >> 4) * 4;
            float* cp = C + rw * ldc + col;
            #pragma unroll
            for (int j = 0; j < 4; j++)
                cp[(long)j * ldc] = acc[mf][nf][j];
        }
    }
}

// ---------------------------------------------------------------------------
// Generic fp32 GEMM (kept for x_proj / dt_proj): C = A @ Bw^T
// EPI: 0 = none, 1 = softplus(x + bias[n])
// ---------------------------------------------------------------------------
template <int EPI>
__global__ __launch_bounds__(256) void gemm_nt(
    const float* __restrict__ A, int lda,
    const float* __restrict__ Bw, int ldb,
    float* __restrict__ C, int ldc,
    int M, int N, int K,
    const float* __restrict__ bias)
{
    __shared__ float As[16][68];
    __shared__ float Bs[16][68];
    const int tid = threadIdx.x;
    const int m0 = blockIdx.y * 64;
    const int n0 = blockIdx.x * 64;
    const int tx = tid & 15;
    const int ty = tid >> 4;
    const int lrow = tid >> 2;
    const int lk4 = (tid & 3) << 2;

    float acc[4][4] = {};

    for (int k0 = 0; k0 < K; k0 += 16) {
        float4 av = make_float4(0.f, 0.f, 0.f, 0.f);
        float4 bv = make_float4(0.f, 0.f, 0.f, 0.f);
        const int arow = m0 + lrow;
        if (arow < M)
            av = *reinterpret_cast<const float4*>(A + (long)arow * lda + k0 + lk4);
        const int brow = n0 + lrow;
        if (brow < N)
            bv = *reinterpret_cast<const float4*>(Bw + (long)brow * ldb + k0 + lk4);
        __syncthreads();
        As[lk4 + 0][lrow] = av.x; As[lk4 + 1][lrow] = av.y;
        As[lk4 + 2][lrow] = av.z; As[lk4 + 3][lrow] = av.w;
        Bs[lk4 + 0][lrow] = bv.x; Bs[lk4 + 1][lrow] = bv.y;
        Bs[lk4 + 2][lrow] = bv.z; Bs[lk4 + 3][lrow] = bv.w;
        __syncthreads();
        #pragma unroll
        for (int k = 0; k < 16; k++) {
            float a[4], b[4];
            #pragma unroll
            for (int i = 0; i < 4; i++) a[i] = As[k][ty * 4 + i];
            #pragma unroll
            for (int j = 0; j < 4; j++) b[j] = Bs[k][tx * 4 + j];
            #pragma unroll
            for (int i = 0; i < 4; i++)
                #pragma unroll
                for (int j = 0; j < 4; j++)
                    acc[i][j] = fmaf(a[i], b[j], acc[i][j]);
        }
    }

    #pragma unroll
    for (int i = 0; i < 4; i++) {
        const int m = m0 + ty * 4 + i;
        if (m >= M) continue;
        #pragma unroll
        for (int j = 0; j < 4; j++) {
            const int n = n0 + tx * 4 + j;
            if (n >= N) continue;
            float v = acc[i][j];
            if (EPI == 1) v = softplus_f(v + bias[n]);
            C[(long)m * ldc + n] = v;
        }
    }
}

// ---------------------------------------------------------------------------
// Depthwise causal conv (fwd) + anticausal conv (bwd), + bias + SiLU.
// ---------------------------------------------------------------------------
__global__ __launch_bounds__(256) void conv_silu_k(
    const float* __restrict__ xz,
    const float* __restrict__ cw, const float* __restrict__ cb,
    const float* __restrict__ cwb, const float* __restrict__ cbb,
    float* __restrict__ outf, float* __restrict__ outb, int nt)
{
    const long idx = (long)blockIdx.x * 256 + threadIdx.x;
    if (idx >= (long)nt * DI) return;
    const int d = (int)(idx % DI);
    const long t = idx / DI;
    const int l = (int)(t % LSEQ);
    const float* base = xz + t * (2 * DI) + d;

    float af = cb[d];
    float ab = cbb[d];
    #pragma unroll
    for (int k = 0; k < 4; k++) {
        const int dl = k - 3;
        if (l + dl >= 0) af += cw[d * 4 + k] * base[(long)dl * (2 * DI)];
        const int dl2 = 3 - k;
        if (l + dl2 < LSEQ) ab += cwb[d * 4 + k] * base[(long)dl2 * (2 * DI)];
    }
    outf[idx] = silu_f(af);
    outb[idx] = silu_f(ab);
}

// ---------------------------------------------------------------------------
// Selective scan, both directions (blockIdx.z = dir). 8-step register tiles,
// double-buffered. y overwrites the dt buffer in place.
// ---------------------------------------------------------------------------
#define TS 8
#define NTILE (LSEQ / TS)

__global__ __launch_bounds__(256) void scan_k(
    const float* __restrict__ uf, float* __restrict__ yf, const float* __restrict__ dblf,
    const float* __restrict__ Alf, const float* __restrict__ Df,
    const float* __restrict__ ub, float* __restrict__ yb, const float* __restrict__ dblb,
    const float* __restrict__ Alb, const float* __restrict__ Db)
{
    const int dir = blockIdx.z;
    const float* u_   = dir ? ub   : uf;
    float*       y_   = dir ? yb   : yf;
    const float* dbl_ = dir ? dblb : dblf;
    const float* Al   = dir ? Alb  : Alf;
    const float* Dp   = dir ? Db   : Df;

    const int tid = threadIdx.x;
    const int n = tid & 15;
    const int dg = tid >> 4;
    const int d = blockIdx.x * 16 + dg;
    const int b = blockIdx.y;

    const float An = -__expf(Al[d * NST + n]);
    const float Dd = Dp[d];
    float h = 0.f;
    const long tbase = (long)b * LSEQ;
    const int stp = dir ? -1 : 1;
    const int l0  = dir ? (LSEQ - 1) : 0;

#define LOADT(U, DT, BV, CV, tile)                                      \
    {                                                                   \
        _Pragma("unroll")                                               \
        for (int i = 0; i < TS; i++) {                                  \
            const int l = l0 + ((tile) * TS + i) * stp;                 \
            const long t = tbase + l;                                   \
            U[i]  = u_[t * DI + d];                                     \
            DT[i] = y_[t * DI + d];                                     \
            BV[i] = dbl_[t * 80 + DTR + n];                             \
            CV[i] = dbl_[t * 80 + DTR + NST + n];                       \
        }                                                               \
    }

#define COMPT(U, DT, BV, CV, tile)                                      \
    {                                                                   \
        _Pragma("unroll")                                               \
        for (int i = 0; i < TS; i++) {                                  \
            const float dAv = __expf(DT[i] * An);                       \
            h = h * dAv + (DT[i] * U[i]) * BV[i];                       \
            float p = h * CV[i];                                        \
            p += __shfl_xor(p, 1, 16);                                  \
            p += __shfl_xor(p, 2, 16);                                  \
            p += __shfl_xor(p, 4, 16);                                  \
            p += __shfl_xor(p, 8, 16);                                  \
            if (n == 0) {                                               \
                const int l = l0 + ((tile) * TS + i) * stp;             \
                y_[(tbase + l) * DI + d] = p + U[i] * Dd;               \
            }                                                           \
        }                                                               \
    }

    float uA[TS], dA_[TS], BA[TS], CA[TS];
    float uB[TS], dB_[TS], BB[TS], CB2[TS];

    LOADT(uA, dA_, BA, CA, 0);
    for (int tile = 0; tile < NTILE; tile += 2) {
        LOADT(uB, dB_, BB, CB2, tile + 1);
        COMPT(uA, dA_, BA, CA, tile);
        if (tile + 2 < NTILE) LOADT(uA, dA_, BA, CA, tile + 2);
        COMPT(uB, dB_, BB, CB2, tile + 1);
    }
#undef LOADT
#undef COMPT
}

// ---------------------------------------------------------------------------
// Gate: g = (yf + yb) * silu(z) -> bf16 (feeds out_proj MFMA GEMM)
// ---------------------------------------------------------------------------
__global__ __launch_bounds__(256) void gate_k(
    const float* __restrict__ yf, const float* __restrict__ yb,
    const float* __restrict__ xz, __hip_bfloat16* __restrict__ g, int nt)
{
    const long idx = (long)blockIdx.x * 256 + threadIdx.x;
    if (idx >= (long)nt * DI) return;
    const int d = (int)(idx % DI);
    const long t = idx / DI;
    const float z = xz[t * (2 * DI) + DI + d];
    g[idx] = __float2bfloat16((yf[idx] + yb[idx]) * silu_f(z));
}

// ---------------------------------------------------------------------------
// out = xin + rmsnorm(mo, w);  one block per token
// ---------------------------------------------------------------------------
__global__ __launch_bounds__(256) void rmsnorm_res_k(
    const float* __restrict__ mo, const float* __restrict__ xin,
    const float* __restrict__ w, float* __restrict__ out)
{
    const int t = blockIdx.x;
    const int tid = threadIdx.x;
    const long base = (long)t * DM;
    const float v0 = mo[base + tid];
    const float v1 = mo[base + tid + 256];
    const float v2 = mo[base + tid + 512];
    float ss = v0 * v0 + v1 * v1 + v2 * v2;
    #pragma unroll
    for (int m = 1; m < 64; m <<= 1) ss += __shfl_xor(ss, m, 64);
    __shared__ float red[4];
    if ((tid & 63) == 0) red[tid >> 6] = ss;
    __syncthreads();
    const float tot = red[0] + red[1] + red[2] + red[3];
    const float sc = rsqrtf(tot * (1.f / DM) + 1e-5f);
    out[base + tid]       = xin[base + tid]       + v0 * sc * w[tid];
    out[base + tid + 256] = xin[base + tid + 256] + v1 * sc * w[tid + 256];
    out[base + tid + 512] = xin[base + tid + 512] + v2 * sc * w[tid + 512];
}

// ---------------------------------------------------------------------------
extern "C" void kernel_launch(void* const* d_in, const int* in_sizes, int n_in,
                              void* d_out, int out_size, void* d_ws, size_t ws_size,
                              hipStream_t stream)
{
    const float* m_x         = (const float*)d_in[0];
    const float* n_x         = (const float*)d_in[1];
    const float* in_proj_w   = (const float*)d_in[2];
    const float* conv_w      = (const float*)d_in[3];
    const float* conv_b      = (const float*)d_in[4];
    const float* x_proj_w    = (const float*)d_in[5];
    const float* dt_proj_w   = (const float*)d_in[6];
    const float* dt_proj_b   = (const float*)d_in[7];
    const float* A_log       = (const float*)d_in[8];
    const float* Dp          = (const float*)d_in[9];
    const float* conv_w_b    = (const float*)d_in[10];
    const float* conv_b_b    = (const float*)d_in[11];
    const float* x_proj_w_b  = (const float*)d_in[12];
    const float* dt_proj_w_b = (const float*)d_in[13];
    const float* dt_proj_b_b = (const float*)d_in[14];
    const float* A_log_b     = (const float*)d_in[15];
    const float* D_b         = (const float*)d_in[16];
    const float* out_proj_w  = (const float*)d_in[17];
    const float* norm1_w     = (const float*)d_in[18];
    const float* norm2_w     = (const float*)d_in[19];

    // ---- workspace layout: fixed bf16 weight copies first, then per-chunk
    const long W_IN  = (long)(2 * DI) * DM;   // 2,359,296 elements
    const long W_OUT = (long)DM * DI;         // 1,179,648 elements
    char* wsc = (char*)d_ws;
    __hip_bfloat16* wbf_in  = (__hip_bfloat16*)wsc;
    __hip_bfloat16* wbf_out = wbf_in + W_IN;
    char* chunk_base = (char*)(wbf_out + W_OUT);
    const size_t fixed_bytes = (size_t)(W_IN + W_OUT) * 2;

    // per-batch floats: xz 3072 + convf/b 2*1536 + dblf/b 2*80 + dtf/b 2*1536
    //                 + abf (1536 bf16 = 768 f32-equiv)   per token
    const long PBF = (long)LSEQ * (3072 + 2 * 1536 + 2 * 80 + 2 * 1536 + 768);
    int CB = (int)((ws_size - fixed_bytes) / ((size_t)PBF * 4));
    if (CB < 1) CB = 1;
    if (CB > NB) CB = NB;

    const long CT = (long)CB * LSEQ;
    float* fb    = (float*)chunk_base;
    float* xz    = fb;                       // CT * 3072
    float* convf = xz    + CT * 2 * DI;      // CT * 1536
    float* convb = convf + CT * DI;          // CT * 1536
    float* dblf  = convb + CT * DI;          // CT * 80
    float* dblb  = dblf  + CT * 80;          // CT * 80
    float* dtf   = dblb  + CT * 80;          // CT * 1536 (scan -> yf in place)
    float* dtb   = dtf   + CT * DI;          // CT * 1536 (scan -> yb in place)
    __hip_bfloat16* abf = (__hip_bfloat16*)(dtb + CT * DI);  // CT * 1536 bf16

    const dim3 blk(256);

    // convert projection weights to bf16 once
    f2bf_k<<<dim3((W_IN / 4 + 255) / 256), blk, 0, stream>>>(in_proj_w, wbf_in, W_IN / 4);
    f2bf_k<<<dim3((W_OUT / 4 + 255) / 256), blk, 0, stream>>>(out_proj_w, wbf_out, W_OUT / 4);

    for (int which = 0; which < 2; which++) {
        const float* xin0 = which ? n_x : m_x;
        const float* nw   = which ? norm2_w : norm1_w;
        float* out0 = (float*)d_out + (long)which * TT * DM;

        for (int b0 = 0; b0 < NB; b0 += CB) {
            const int cb = (NB - b0) < CB ? (NB - b0) : CB;
            const int nt = cb * LSEQ;
            const float* xin = xin0 + (long)b0 * LSEQ * DM;
            float* outp = out0 + (long)b0 * LSEQ * DM;

            // A -> bf16, then in_proj via MFMA:
            // xz[nt,3072] = xin_bf[nt,768] @ wbf_in[3072,768]^T
            f2bf_k<<<dim3(((long)nt * DM / 4 + 255) / 256), blk, 0, stream>>>(
                xin, abf, (long)nt * DM / 4);
            gemm_bf16<<<dim3((2 * DI) / 128, nt / 128), blk, 0, stream>>>(
                abf, DM, wbf_in, DM, xz, 2 * DI, DM);

            // depthwise conv + silu, both directions
            conv_silu_k<<<dim3(((long)nt * DI + 255) / 256), blk, 0, stream>>>(
                xz, conv_w, conv_b, conv_w_b, conv_b_b, convf, convb, nt);

            // x_proj (fp32): dbl[nt,80] = conv @ x_proj_w[80,1536]^T
            gemm_nt<0><<<dim3(2, nt / 64), blk, 0, stream>>>(
                convf, DI, x_proj_w, DI, dblf, 80, nt, 80, DI, nullptr);
            gemm_nt<0><<<dim3(2, nt / 64), blk, 0, stream>>>(
                convb, DI, x_proj_w_b, DI, dblb, 80, nt, 80, DI, nullptr);

            // dt_proj (fp32): dt[nt,1536] = softplus(dbl[:, :48] @ w^T + b)
            gemm_nt<1><<<dim3(DI / 64, nt / 64), blk, 0, stream>>>(
                dblf, 80, dt_proj_w, DTR, dtf, DI, nt, DI, DTR, dt_proj_b);
            gemm_nt<1><<<dim3(DI / 64, nt / 64), blk, 0, stream>>>(
                dblb, 80, dt_proj_w_b, DTR, dtb, DI, nt, DI, DTR, dt_proj_b_b);

            // selective scan, fwd + bwd (y overwrites dt buffers)
            scan_k<<<dim3(DI / 16, cb, 2), blk, 0, stream>>>(
                convf, dtf, dblf, A_log, Dp,
                convb, dtb, dblb, A_log_b, D_b);

            // gate -> bf16 A operand for out_proj
            gate_k<<<dim3(((long)nt * DI + 255) / 256), blk, 0, stream>>>(
                dtf, dtb, xz, abf, nt);

            // out_proj via MFMA: mo[nt,768] = g_bf @ wbf_out[768,1536]^T
            gemm_bf16<<<dim3(DM / 128, nt / 128), blk, 0, stream>>>(
                abf, DI, wbf_out, DI, convb, DM, DI);

            // residual + rmsnorm
            rmsnorm_res_k<<<dim3(nt), blk, 0, stream>>>(convb, xin, nw, outp);
        }
    }
}

// Round 5
// 2451.082 us; speedup vs baseline: 1.9122x; 1.0943x over previous
//
#include <hip/hip_runtime.h>
#include <hip/hip_bf16.h>
#include <math.h>

// Problem constants (from reference)
#define NB   8
#define LSEQ 1024
#define DM   768
#define DI   1536
#define NST  16
#define DTR  48
#define TT   (NB * LSEQ)   // 8192 tokens per input

typedef __attribute__((ext_vector_type(8))) short bf16x8;
typedef __attribute__((ext_vector_type(4))) float f32x4;

__device__ __forceinline__ float silu_f(float x) { return x / (1.f + __expf(-x)); }
__device__ __forceinline__ float softplus_f(float x) { return x > 20.f ? x : log1pf(__expf(x)); }

// ---------------------------------------------------------------------------
// fp32 -> bf16 conversion (n must be a multiple of 4)
// ---------------------------------------------------------------------------
__global__ __launch_bounds__(256) void f2bf_k(
    const float* __restrict__ in, __hip_bfloat16* __restrict__ out, long n4)
{
    const long i = (long)blockIdx.x * 256 + threadIdx.x;
    if (i >= n4) return;
    const float4 v = ((const float4*)in)[i];
    out[i * 4 + 0] = __float2bfloat16(v.x);
    out[i * 4 + 1] = __float2bfloat16(v.y);
    out[i * 4 + 2] = __float2bfloat16(v.z);
    out[i * 4 + 3] = __float2bfloat16(v.w);
}

// ---------------------------------------------------------------------------
// bf16 MFMA GEMM: C[M,N] (fp32) = A[M,K] @ Bw[N,K]^T, A/Bw bf16 row-major,
// K contiguous. 128x128 tile, BK=32, 256 threads = 4 waves (2x2), 4x4
// 16x16x32 fragments per wave. Reg-staged double-buffered LDS with XOR
// swizzle slot^=(row>>1)&3 applied on BOTH write and read sides.
// Requires: M%128==0, N%128==0, K%32==0.
// ---------------------------------------------------------------------------
__global__ __launch_bounds__(256) void gemm_bf16(
    const __hip_bfloat16* __restrict__ A, int lda,
    const __hip_bfloat16* __restrict__ Bw, int ldb,
    float* __restrict__ C, int ldc, int K)
{
    __shared__ short lds[2][8192];      // [buf][ A 128x32 | B 128x32 ] bf16
    const int tid = threadIdx.x;
    const int lane = tid & 63;
    const int wv = tid >> 6;
    const int wm = wv >> 1;             // 0..1
    const int wn = wv & 1;              // 0..1
    const long m0 = (long)blockIdx.y * 128;
    const long n0 = (long)blockIdx.x * 128;

    const int srow = tid >> 2;          // 0..63
    const int skslot = tid & 3;
    const int sswz = skslot ^ ((srow >> 1) & 3);
    const __hip_bfloat16* gA0 = A  + (m0 + srow) * (long)lda + skslot * 8;
    const __hip_bfloat16* gA1 = gA0 + 64l * lda;
    const __hip_bfloat16* gB0 = Bw + (n0 + srow) * (long)ldb + skslot * 8;
    const __hip_bfloat16* gB1 = gB0 + 64l * ldb;
    const int wA0 = srow * 32 + sswz * 8;
    const int wA1 = (srow + 64) * 32 + sswz * 8;
    const int wB0 = 4096 + srow * 32 + sswz * 8;
    const int wB1 = 4096 + (srow + 64) * 32 + sswz * 8;

    const int frow = lane & 15;         // fragment row-in-16
    const int fk = lane >> 4;           // fragment k-slot 0..3

    f32x4 acc[4][4] = {};

    const int NK = K / 32;
    int4 r0, r1, r2, r3;
    r0 = *(const int4*)gA0; r1 = *(const int4*)gA1;
    r2 = *(const int4*)gB0; r3 = *(const int4*)gB1;
    *(int4*)&lds[0][wA0] = r0; *(int4*)&lds[0][wA1] = r1;
    *(int4*)&lds[0][wB0] = r2; *(int4*)&lds[0][wB1] = r3;

    for (int ks = 0; ks < NK; ks++) {
        const int cur = ks & 1;
        if (ks + 1 < NK) {              // issue next tile's global loads early
            const long ko = (long)(ks + 1) * 32;
            r0 = *(const int4*)(gA0 + ko); r1 = *(const int4*)(gA1 + ko);
            r2 = *(const int4*)(gB0 + ko); r3 = *(const int4*)(gB1 + ko);
        }
        __syncthreads();                // staging of `cur` visible to all
        bf16x8 af[4], bfr[4];
        #pragma unroll
        for (int mf = 0; mf < 4; mf++) {
            const int row = wm * 64 + mf * 16 + frow;
            const int sl = fk ^ ((row >> 1) & 3);
            af[mf] = *(const bf16x8*)&lds[cur][row * 32 + sl * 8];
        }
        #pragma unroll
        for (int nf = 0; nf < 4; nf++) {
            const int row = wn * 64 + nf * 16 + frow;
            const int sl = fk ^ ((row >> 1) & 3);
            bfr[nf] = *(const bf16x8*)&lds[cur][4096 + row * 32 + sl * 8];
        }
        #pragma unroll
        for (int mf = 0; mf < 4; mf++)
            #pragma unroll
            for (int nf = 0; nf < 4; nf++)
                acc[mf][nf] = __builtin_amdgcn_mfma_f32_16x16x32_bf16(
                    af[mf], bfr[nf], acc[mf][nf], 0, 0, 0);
        if (ks + 1 < NK) {              // write next tile into other buffer
            const int nb = cur ^ 1;
            *(int4*)&lds[nb][wA0] = r0; *(int4*)&lds[nb][wA1] = r1;
            *(int4*)&lds[nb][wB0] = r2; *(int4*)&lds[nb][wB1] = r3;
        }
    }

    // epilogue: C/D layout col=lane&15, row=(lane>>4)*4+j  [m89-verified]
    #pragma unroll
    for (int mf = 0; mf < 4; mf++) {
        #pragma unroll
        for (int nf = 0; nf < 4; nf++) {
            const long col = n0 + wn * 64 + nf * 16 + (lane & 15);
            const long rw = m0 + wm * 64 + mf * 16 + (lane >> 4) * 4;
            float* cp = C + rw * ldc + col;
            #pragma unroll
            for (int j = 0; j < 4; j++)
                cp[(long)j * ldc] = acc[mf][nf][j];
        }
    }
}

// ---------------------------------------------------------------------------
// Generic fp32 GEMM (kept for x_proj / dt_proj): C = A @ Bw^T
// EPI: 0 = none, 1 = softplus(x + bias[n])
// ---------------------------------------------------------------------------
template <int EPI>
__global__ __launch_bounds__(256) void gemm_nt(
    const float* __restrict__ A, int lda,
    const float* __restrict__ Bw, int ldb,
    float* __restrict__ C, int ldc,
    int M, int N, int K,
    const float* __restrict__ bias)
{
    __shared__ float As[16][68];
    __shared__ float Bs[16][68];
    const int tid = threadIdx.x;
    const int m0 = blockIdx.y * 64;
    const int n0 = blockIdx.x * 64;
    const int tx = tid & 15;
    const int ty = tid >> 4;
    const int lrow = tid >> 2;
    const int lk4 = (tid & 3) << 2;

    float acc[4][4] = {};

    for (int k0 = 0; k0 < K; k0 += 16) {
        float4 av = make_float4(0.f, 0.f, 0.f, 0.f);
        float4 bv = make_float4(0.f, 0.f, 0.f, 0.f);
        const int arow = m0 + lrow;
        if (arow < M)
            av = *reinterpret_cast<const float4*>(A + (long)arow * lda + k0 + lk4);
        const int brow = n0 + lrow;
        if (brow < N)
            bv = *reinterpret_cast<const float4*>(Bw + (long)brow * ldb + k0 + lk4);
        __syncthreads();
        As[lk4 + 0][lrow] = av.x; As[lk4 + 1][lrow] = av.y;
        As[lk4 + 2][lrow] = av.z; As[lk4 + 3][lrow] = av.w;
        Bs[lk4 + 0][lrow] = bv.x; Bs[lk4 + 1][lrow] = bv.y;
        Bs[lk4 + 2][lrow] = bv.z; Bs[lk4 + 3][lrow] = bv.w;
        __syncthreads();
        #pragma unroll
        for (int k = 0; k < 16; k++) {
            float a[4], b[4];
            #pragma unroll
            for (int i = 0; i < 4; i++) a[i] = As[k][ty * 4 + i];
            #pragma unroll
            for (int j = 0; j < 4; j++) b[j] = Bs[k][tx * 4 + j];
            #pragma unroll
            for (int i = 0; i < 4; i++)
                #pragma unroll
                for (int j = 0; j < 4; j++)
                    acc[i][j] = fmaf(a[i], b[j], acc[i][j]);
        }
    }

    #pragma unroll
    for (int i = 0; i < 4; i++) {
        const int m = m0 + ty * 4 + i;
        if (m >= M) continue;
        #pragma unroll
        for (int j = 0; j < 4; j++) {
            const int n = n0 + tx * 4 + j;
            if (n >= N) continue;
            float v = acc[i][j];
            if (EPI == 1) v = softplus_f(v + bias[n]);
            C[(long)m * ldc + n] = v;
        }
    }
}

// ---------------------------------------------------------------------------
// Depthwise causal conv (fwd) + anticausal conv (bwd), + bias + SiLU.
// ---------------------------------------------------------------------------
__global__ __launch_bounds__(256) void conv_silu_k(
    const float* __restrict__ xz,
    const float* __restrict__ cw, const float* __restrict__ cb,
    const float* __restrict__ cwb, const float* __restrict__ cbb,
    float* __restrict__ outf, float* __restrict__ outb, int nt)
{
    const long idx = (long)blockIdx.x * 256 + threadIdx.x;
    if (idx >= (long)nt * DI) return;
    const int d = (int)(idx % DI);
    const long t = idx / DI;
    const int l = (int)(t % LSEQ);
    const float* base = xz + t * (2 * DI) + d;

    float af = cb[d];
    float ab = cbb[d];
    #pragma unroll
    for (int k = 0; k < 4; k++) {
        const int dl = k - 3;
        if (l + dl >= 0) af += cw[d * 4 + k] * base[(long)dl * (2 * DI)];
        const int dl2 = 3 - k;
        if (l + dl2 < LSEQ) ab += cwb[d * 4 + k] * base[(long)dl2 * (2 * DI)];
    }
    outf[idx] = silu_f(af);
    outb[idx] = silu_f(ab);
}

// ---------------------------------------------------------------------------
// Selective scan, both directions (blockIdx.z = dir).
// Layout: 4 threads per channel (sub = tid&3), 4 states per thread, so a
// 256-thread block covers 64 consecutive channels. Per step:
//   u/dt broadcast to the 4 lanes of a channel, B/C as one float4 each,
//   4 register h-recurrences, 2-shfl reduce, sub==0 lanes store (a wave
//   stores 16 consecutive channels = 64 B contiguous).
// 8-step register tiles, double-buffered (all compile-time indices).
// y overwrites the dt buffer in place (tile t+1 loads precede tile t stores;
// disjoint token indices).
// ---------------------------------------------------------------------------
#define TS 8
#define NTILE (LSEQ / TS)

__global__ __launch_bounds__(256) void scan_k(
    const float* __restrict__ uf, float* __restrict__ yf, const float* __restrict__ dblf,
    const float* __restrict__ Alf, const float* __restrict__ Df,
    const float* __restrict__ ub, float* __restrict__ yb, const float* __restrict__ dblb,
    const float* __restrict__ Alb, const float* __restrict__ Db)
{
    const int dir = blockIdx.z;
    const float* u_   = dir ? ub   : uf;
    float*       y_   = dir ? yb   : yf;
    const float* dbl_ = dir ? dblb : dblf;
    const float* Al   = dir ? Alb  : Alf;
    const float* Dp   = dir ? Db   : Df;

    const int tid = threadIdx.x;
    const int sub = tid & 3;            // state group 0..3 (states sub*4..sub*4+3)
    const int chl = tid >> 2;           // channel-in-block 0..63
    const int d = blockIdx.x * 64 + chl;
    const int b = blockIdx.y;

    float An0 = -__expf(Al[d * NST + sub * 4 + 0]);
    float An1 = -__expf(Al[d * NST + sub * 4 + 1]);
    float An2 = -__expf(Al[d * NST + sub * 4 + 2]);
    float An3 = -__expf(Al[d * NST + sub * 4 + 3]);
    const float Dd = Dp[d];
    float h0 = 0.f, h1 = 0.f, h2 = 0.f, h3 = 0.f;
    const long tbase = (long)b * LSEQ;
    const int stp = dir ? -1 : 1;
    const int l0  = dir ? (LSEQ - 1) : 0;

#define LOADT(U, DT, BV, CV, tile)                                      \
    {                                                                   \
        _Pragma("unroll")                                               \
        for (int i = 0; i < TS; i++) {                                  \
            const int l = l0 + ((tile) * TS + i) * stp;                 \
            const long t = tbase + l;                                   \
            U[i]  = u_[t * DI + d];                                     \
            DT[i] = y_[t * DI + d];                                     \
            BV[i] = *(const float4*)&dbl_[t * 80 + DTR + sub * 4];      \
            CV[i] = *(const float4*)&dbl_[t * 80 + DTR + NST + sub * 4];\
        }                                                               \
    }

#define COMPT(U, DT, BV, CV, tile)                                      \
    {                                                                   \
        _Pragma("unroll")                                               \
        for (int i = 0; i < TS; i++) {                                  \
            const float dtu = DT[i] * U[i];                             \
            h0 = h0 * __expf(DT[i] * An0) + dtu * BV[i].x;              \
            h1 = h1 * __expf(DT[i] * An1) + dtu * BV[i].y;              \
            h2 = h2 * __expf(DT[i] * An2) + dtu * BV[i].z;              \
            h3 = h3 * __expf(DT[i] * An3) + dtu * BV[i].w;              \
            float p = h0 * CV[i].x + h1 * CV[i].y                       \
                    + h2 * CV[i].z + h3 * CV[i].w;                      \
            p += __shfl_xor(p, 1, 4);                                   \
            p += __shfl_xor(p, 2, 4);                                   \
            if (sub == 0) {                                             \
                const int l = l0 + ((tile) * TS + i) * stp;             \
                y_[(tbase + l) * DI + d] = p + U[i] * Dd;               \
            }                                                           \
        }                                                               \
    }

    float uA[TS], dA_[TS]; float4 BA[TS], CA[TS];
    float uB[TS], dB_[TS]; float4 BB[TS], CB2[TS];

    LOADT(uA, dA_, BA, CA, 0);
    for (int tile = 0; tile < NTILE; tile += 2) {
        LOADT(uB, dB_, BB, CB2, tile + 1);          // NTILE even: always valid
        COMPT(uA, dA_, BA, CA, tile);
        if (tile + 2 < NTILE) LOADT(uA, dA_, BA, CA, tile + 2);
        COMPT(uB, dB_, BB, CB2, tile + 1);
    }
#undef LOADT
#undef COMPT
}

// ---------------------------------------------------------------------------
// Gate: g = (yf + yb) * silu(z) -> bf16 (feeds out_proj MFMA GEMM)
// ---------------------------------------------------------------------------
__global__ __launch_bounds__(256) void gate_k(
    const float* __restrict__ yf, const float* __restrict__ yb,
    const float* __restrict__ xz, __hip_bfloat16* __restrict__ g, int nt)
{
    const long idx = (long)blockIdx.x * 256 + threadIdx.x;
    if (idx >= (long)nt * DI) return;
    const int d = (int)(idx % DI);
    const long t = idx / DI;
    const float z = xz[t * (2 * DI) + DI + d];
    g[idx] = __float2bfloat16((yf[idx] + yb[idx]) * silu_f(z));
}

// ---------------------------------------------------------------------------
// out = xin + rmsnorm(mo, w);  one block per token
// ---------------------------------------------------------------------------
__global__ __launch_bounds__(256) void rmsnorm_res_k(
    const float* __restrict__ mo, const float* __restrict__ xin,
    const float* __restrict__ w, float* __restrict__ out)
{
    const int t = blockIdx.x;
    const int tid = threadIdx.x;
    const long base = (long)t * DM;
    const float v0 = mo[base + tid];
    const float v1 = mo[base + tid + 256];
    const float v2 = mo[base + tid + 512];
    float ss = v0 * v0 + v1 * v1 + v2 * v2;
    #pragma unroll
    for (int m = 1; m < 64; m <<= 1) ss += __shfl_xor(ss, m, 64);
    __shared__ float red[4];
    if ((tid & 63) == 0) red[tid >> 6] = ss;
    __syncthreads();
    const float tot = red[0] + red[1] + red[2] + red[3];
    const float sc = rsqrtf(tot * (1.f / DM) + 1e-5f);
    out[base + tid]       = xin[base + tid]       + v0 * sc * w[tid];
    out[base + tid + 256] = xin[base + tid + 256] + v1 * sc * w[tid + 256];
    out[base + tid + 512] = xin[base + tid + 512] + v2 * sc * w[tid + 512];
}

// ---------------------------------------------------------------------------
extern "C" void kernel_launch(void* const* d_in, const int* in_sizes, int n_in,
                              void* d_out, int out_size, void* d_ws, size_t ws_size,
                              hipStream_t stream)
{
    const float* m_x         = (const float*)d_in[0];
    const float* n_x         = (const float*)d_in[1];
    const float* in_proj_w   = (const float*)d_in[2];
    const float* conv_w      = (const float*)d_in[3];
    const float* conv_b      = (const float*)d_in[4];
    const float* x_proj_w    = (const float*)d_in[5];
    const float* dt_proj_w   = (const float*)d_in[6];
    const float* dt_proj_b   = (const float*)d_in[7];
    const float* A_log       = (const float*)d_in[8];
    const float* Dp          = (const float*)d_in[9];
    const float* conv_w_b    = (const float*)d_in[10];
    const float* conv_b_b    = (const float*)d_in[11];
    const float* x_proj_w_b  = (const float*)d_in[12];
    const float* dt_proj_w_b = (const float*)d_in[13];
    const float* dt_proj_b_b = (const float*)d_in[14];
    const float* A_log_b     = (const float*)d_in[15];
    const float* D_b         = (const float*)d_in[16];
    const float* out_proj_w  = (const float*)d_in[17];
    const float* norm1_w     = (const float*)d_in[18];
    const float* norm2_w     = (const float*)d_in[19];

    // ---- workspace layout: fixed bf16 weight copies first, then per-chunk
    const long W_IN  = (long)(2 * DI) * DM;   // 2,359,296 elements
    const long W_OUT = (long)DM * DI;         // 1,179,648 elements
    char* wsc = (char*)d_ws;
    __hip_bfloat16* wbf_in  = (__hip_bfloat16*)wsc;
    __hip_bfloat16* wbf_out = wbf_in + W_IN;
    char* chunk_base = (char*)(wbf_out + W_OUT);
    const size_t fixed_bytes = (size_t)(W_IN + W_OUT) * 2;

    // per-batch floats: xz 3072 + convf/b 2*1536 + dblf/b 2*80 + dtf/b 2*1536
    //                 + abf (1536 bf16 = 768 f32-equiv)   per token
    const long PBF = (long)LSEQ * (3072 + 2 * 1536 + 2 * 80 + 2 * 1536 + 768);
    int CB = (int)((ws_size - fixed_bytes) / ((size_t)PBF * 4));
    if (CB < 1) CB = 1;
    if (CB > NB) CB = NB;

    const long CT = (long)CB * LSEQ;
    float* fb    = (float*)chunk_base;
    float* xz    = fb;                       // CT * 3072
    float* convf = xz    + CT * 2 * DI;      // CT * 1536
    float* convb = convf + CT * DI;          // CT * 1536
    float* dblf  = convb + CT * DI;          // CT * 80
    float* dblb  = dblf  + CT * 80;          // CT * 80
    float* dtf   = dblb  + CT * 80;          // CT * 1536 (scan -> yf in place)
    float* dtb   = dtf   + CT * DI;          // CT * 1536 (scan -> yb in place)
    __hip_bfloat16* abf = (__hip_bfloat16*)(dtb + CT * DI);  // CT * 1536 bf16

    const dim3 blk(256);

    // convert projection weights to bf16 once
    f2bf_k<<<dim3((W_IN / 4 + 255) / 256), blk, 0, stream>>>(in_proj_w, wbf_in, W_IN / 4);
    f2bf_k<<<dim3((W_OUT / 4 + 255) / 256), blk, 0, stream>>>(out_proj_w, wbf_out, W_OUT / 4);

    for (int which = 0; which < 2; which++) {
        const float* xin0 = which ? n_x : m_x;
        const float* nw   = which ? norm2_w : norm1_w;
        float* out0 = (float*)d_out + (long)which * TT * DM;

        for (int b0 = 0; b0 < NB; b0 += CB) {
            const int cb = (NB - b0) < CB ? (NB - b0) : CB;
            const int nt = cb * LSEQ;
            const float* xin = xin0 + (long)b0 * LSEQ * DM;
            float* outp = out0 + (long)b0 * LSEQ * DM;

            // A -> bf16, then in_proj via MFMA:
            // xz[nt,3072] = xin_bf[nt,768] @ wbf_in[3072,768]^T
            f2bf_k<<<dim3(((long)nt * DM / 4 + 255) / 256), blk, 0, stream>>>(
                xin, abf, (long)nt * DM / 4);
            gemm_bf16<<<dim3((2 * DI) / 128, nt / 128), blk, 0, stream>>>(
                abf, DM, wbf_in, DM, xz, 2 * DI, DM);

            // depthwise conv + silu, both directions
            conv_silu_k<<<dim3(((long)nt * DI + 255) / 256), blk, 0, stream>>>(
                xz, conv_w, conv_b, conv_w_b, conv_b_b, convf, convb, nt);

            // x_proj (fp32): dbl[nt,80] = conv @ x_proj_w[80,1536]^T
            gemm_nt<0><<<dim3(2, nt / 64), blk, 0, stream>>>(
                convf, DI, x_proj_w, DI, dblf, 80, nt, 80, DI, nullptr);
            gemm_nt<0><<<dim3(2, nt / 64), blk, 0, stream>>>(
                convb, DI, x_proj_w_b, DI, dblb, 80, nt, 80, DI, nullptr);

            // dt_proj (fp32): dt[nt,1536] = softplus(dbl[:, :48] @ w^T + b)
            gemm_nt<1><<<dim3(DI / 64, nt / 64), blk, 0, stream>>>(
                dblf, 80, dt_proj_w, DTR, dtf, DI, nt, DI, DTR, dt_proj_b);
            gemm_nt<1><<<dim3(DI / 64, nt / 64), blk, 0, stream>>>(
                dblb, 80, dt_proj_w_b, DTR, dtb, DI, nt, DI, DTR, dt_proj_b_b);

            // selective scan, fwd + bwd (y overwrites dt buffers)
            scan_k<<<dim3(DI / 64, cb, 2), blk, 0, stream>>>(
                convf, dtf, dblf, A_log, Dp,
                convb, dtb, dblb, A_log_b, D_b);

            // gate -> bf16 A operand for out_proj
            gate_k<<<dim3(((long)nt * DI + 255) / 256), blk, 0, stream>>>(
                dtf, dtb, xz, abf, nt);

            // out_proj via MFMA: mo[nt,768] = g_bf @ wbf_out[768,1536]^T
            gemm_bf16<<<dim3(DM / 128, nt / 128), blk, 0, stream>>>(
                abf, DI, wbf_out, DI, convb, DM, DI);

            // residual + rmsnorm
            rmsnorm_res_k<<<dim3(nt), blk, 0, stream>>>(convb, xin, nw, outp);
        }
    }
}